// Round 11
// baseline (384.717 us; speedup 1.0000x reference)
//
#include <hip/hip_runtime.h>
#include <math.h>

typedef unsigned short u16;
typedef unsigned int u32;
typedef _Float16 f16x8 __attribute__((ext_vector_type(8)));
typedef float f32x4 __attribute__((ext_vector_type(4)));
typedef u16 u16x4 __attribute__((ext_vector_type(4)));

__device__ __forceinline__ u16 f2h(float x) {
  _Float16 h = (_Float16)x;
  return __builtin_bit_cast(u16, h);
}
__device__ __forceinline__ float h2f(u16 u) {
  return (float)__builtin_bit_cast(_Float16, u);
}

// exact-erf GELU via Abramowitz-Stegun 7.1.26 (|err| <= 1.5e-7)
__device__ __forceinline__ float gelu_erf(float x) {
  const float u = x * 0.70710678118654752f;
  const float s = fabsf(u);
  const float t = __frcp_rn(1.0f + 0.3275911f * s);
  float p = 1.061405429f;
  p = p * t - 1.453152027f;
  p = p * t + 1.421413741f;
  p = p * t - 0.284496736f;
  p = p * t + 0.254829592f;
  const float e = __expf(-s * s);
  float erf = 1.0f - p * t * e;
  erf = u < 0.0f ? -erf : erf;
  return 0.5f * x * (1.0f + erf);
}

__device__ __forceinline__ void gload16(const void* g, void* l) {
  __builtin_amdgcn_global_load_lds(
      (const __attribute__((address_space(1))) void*)g,
      (__attribute__((address_space(3))) void*)l, 16, 0, 0);
}

#define SGB() __builtin_amdgcn_sched_barrier(0)

// ---------------------------------------------------------------------------
// m97-style NT GEMM, fp16, mfma_f32_16x16x32_f16 (proven engine: 0 bank
// conflicts, ~35% MfmaUtil, ~780 TF).  Unchanged from R10.
// EPI: 0 = qkv writer (n<2048 -> qk; else vT direct transpose),
//      1 = scores f32, 2 = +resid(x f32) -> r2 fp16, 3 = +bias+gelu -> fp16,
//      4 = +bias+resid(fp16) -> f32 out
// ---------------------------------------------------------------------------
template <int EPI, bool SWZ>
__global__ __launch_bounds__(256, 4) void gemm_nt(
    const u16* __restrict__ A, const u16* __restrict__ B, int M, int N, int K,
    int lda, int ldb, long zsA, long zsB, long zsC, float* __restrict__ outF,
    u16* __restrict__ outU, u16* __restrict__ outU2,
    const float* __restrict__ aux0, const u16* __restrict__ aux1u) {
  __shared__ char smem[2 * 128 * 64 * 2];  // 32 KiB: sA | sB
  char* sA = smem;
  char* sB = smem + 16384;

  const int tid = threadIdx.x;
  const int lane = tid & 63;
  const int wave = tid >> 6;
  const int z = blockIdx.z;

  int bx = blockIdx.x, by = blockIdx.y;
  if constexpr (SWZ) {
    const int gx = gridDim.x;
    const int nwg = gx * gridDim.y;  // all our per-z grids are %8 == 0
    const int id = by * gx + bx;
    const int q = nwg >> 3;
    const int id2 = (id & 7) * q + (id >> 3);
    bx = id2 % gx;
    by = id2 / gx;
  }
  const long row0 = (long)by * 128;
  const long col0 = (long)bx * 128;

  const u16* __restrict__ Ab = A + (long)z * zsA;
  const u16* __restrict__ Bb = B + (long)z * zsB;

  const int srow = lane >> 3;
  const int sslot = (lane & 7) ^ srow;

  const int wm = (wave >> 1) << 6;
  const int wn = (wave & 1) << 6;
  const int fr = lane & 15;
  const int kgrp = lane >> 4;

  f32x4 acc[4][4] = {};
  const int nk = K >> 6;

  auto stage = [&](int kt) {
#pragma unroll
    for (int c = 0; c < 4; ++c) {
      const int chunk = wave * 4 + c;  // 0..15, 8 rows each
      const int r = chunk * 8 + srow;
      gload16(Ab + (row0 + r) * (long)lda + kt * 64 + sslot * 8,
              sA + chunk * 1024);
      gload16(Bb + (col0 + r) * (long)ldb + kt * 64 + sslot * 8,
              sB + chunk * 1024);
    }
  };

  stage(0);
  for (int kt = 0; kt < nk; ++kt) {
    __syncthreads();
#pragma unroll
    for (int kk = 0; kk < 2; ++kk) {
      f16x8 af[4], bg[4];
#pragma unroll
      for (int i = 0; i < 4; ++i) {
        const int r = wm + i * 16 + fr;
        const int slot = ((kk << 2) | kgrp) ^ (r & 7);
        af[i] = *(const f16x8*)(sA + r * 128 + slot * 16);
      }
#pragma unroll
      for (int j = 0; j < 4; ++j) {
        const int r = wn + j * 16 + fr;
        const int slot = ((kk << 2) | kgrp) ^ (r & 7);
        bg[j] = *(const f16x8*)(sB + r * 128 + slot * 16);
      }
#pragma unroll
      for (int i = 0; i < 4; ++i)
#pragma unroll
        for (int j = 0; j < 4; ++j)
          acc[i][j] = __builtin_amdgcn_mfma_f32_16x16x32_f16(af[i], bg[j],
                                                             acc[i][j], 0, 0, 0);
    }
    __syncthreads();
    if (kt + 1 < nk) stage(kt + 1);
  }

  // epilogue: C/D frag layout (verified): col = lane&15, row = kgrp*4 + r
#pragma unroll
  for (int i = 0; i < 4; ++i) {
    const long m0 = row0 + wm + i * 16 + (kgrp << 2);
#pragma unroll
    for (int j = 0; j < 4; ++j) {
      const long n = col0 + wn + j * 16 + fr;
      if constexpr (EPI == 0) {
        if (n < 2048) {
#pragma unroll
          for (int r = 0; r < 4; ++r)
            outU[(m0 + r) * 2048 + n] = f2h(acc[i][j][r]);
        } else {
          u16x4 V;
#pragma unroll
          for (int r = 0; r < 4; ++r) V[r] = f2h(acc[i][j][r]);
          *(u16x4*)(outU2 + ((m0 >> 11) << 21) + (n - 2048) * 2048 +
                    (m0 & 2047)) = V;
        }
      } else if constexpr (EPI == 1) {
#pragma unroll
        for (int r = 0; r < 4; ++r)
          outF[(long)z * zsC + (m0 + r) * (long)N + n] = acc[i][j][r];
      } else if constexpr (EPI == 2) {
#pragma unroll
        for (int r = 0; r < 4; ++r) {
          const long idx = (long)z * zsC + (m0 + r) * (long)N + n;
          outU[idx] = f2h(acc[i][j][r] + aux0[idx]);
        }
      } else if constexpr (EPI == 3) {
        const float b = aux0[n];
#pragma unroll
        for (int r = 0; r < 4; ++r)
          outU[(m0 + r) * (long)N + n] = f2h(gelu_erf(acc[i][j][r] + b));
      } else {
        const float b = aux0[n];
#pragma unroll
        for (int r = 0; r < 4; ++r) {
          const long idx = (m0 + r) * (long)N + n;
          outF[idx] = acc[i][j][r] + b + h2f(aux1u[idx]);
        }
      }
    }
  }
}

// ---------------------------------------------------------------------------
// 8-phase NT GEMM, FENCED (R11 experiment).  Same schedule/staging map as the
// R3-R6 gemm8 (race-free as analyzed), but with "memory" clobbers on all
// waitcnts and sched_barrier(0) fences pinning each phase's
// {ds_reads | stage-issues | s_barrier | lgkmcnt(0) | MFMA | drain} order so
// hipcc cannot reschedule across phase boundaries (rule #18: bare asm waits
// do NOT order register-only MFMAs; R5/R6 source reorders never survived
// codegen).  Tile 256 x (64*JF), BK=64, 8 waves; NPH phases (JF4->4, JF2->2),
// 16 MFMA per phase.  Per tile s (cur=s&1):
//   p0: reads(A p0-frags + all B); stageA.h0(s+1)->buf[cur^1]
//   p1: reads; stageA.h1(s+1); stageB.h0(s+2)->buf[cur]
//   p2 (JF4): reads; stageB.h1(s+2)
//   last: counted vmcnt(4|2) -> drains exactly tile s+1; B(s+2) in flight.
// EPI: 3 = +bias+gelu -> fp16, 4 = +bias+resid(fp16) -> f32 out
// ---------------------------------------------------------------------------
template <int JF, int NPH, int EPI, bool SWZ>
__global__ __launch_bounds__(512, 2) void gemm8f(
    const u16* __restrict__ A, const u16* __restrict__ B, int M, int N, int K,
    int lda, int ldb, float* __restrict__ outF, u16* __restrict__ outU,
    const float* __restrict__ aux0, const u16* __restrict__ aux1u) {
  constexpr int BUF = 32768 + JF * 8192;
  constexpr int IPP = 8 / NPH;
  extern __shared__ __align__(16) char smem[];

  const int tid = threadIdx.x;
  const int lane = tid & 63;
  const int wave = tid >> 6;

  int bx = blockIdx.x, by = blockIdx.y;
  if constexpr (SWZ) {
    const int gx = gridDim.x;
    const int nwg = gx * gridDim.y;
    const int id = by * gx + bx;
    const int q = nwg >> 3;
    const int id2 = (id & 7) * q + (id >> 3);
    bx = id2 % gx;
    by = id2 / gx;
  }
  const long row0 = (long)by * 256;
  const long col0 = (long)bx * (64 * JF);

  const int srow = lane >> 3;
  const int gslot = (lane & 7) ^ srow;
  const int fr = lane & 15;
  const int kgrp = lane >> 4;
  const int wm = (wave >> 2) << 7;
  const int wn = (wave & 3) * (16 * JF);

  const int nk = K >> 6;

  const int slot0 = kgrp ^ (fr & 7);
  const int offA0 = (wm + fr) * 128 + slot0 * 16;
  const int offA1 = offA0 ^ 64;
  const int offB0 = 32768 + (wn + fr) * 128 + slot0 * 16;
  const int offB1 = offB0 ^ 64;

  const u16* const gA0 = A + (row0 + wave * 16 + srow) * (long)lda + gslot * 8;
  const u16* const gA1 = gA0 + 128 * (long)lda;
  const u16* const gB0 = B + (col0 + wave * 16 + srow) * (long)ldb + gslot * 8;
  const u16* const gB1 = gB0 + 128 * (long)ldb;
  char* const dA = smem + wave * 2048 + lane * 16;
  char* const dB = dA + 32768;

  f32x4 acc[8][JF] = {};
  f16x8 bfrag[2][JF];

  auto stageA = [&](int buf, int kt, int h) {
    const long ko = (long)kt * 64;
    const u16* g = (h ? gA1 : gA0) + ko;
    char* d = dA + buf * BUF + (h ? 16384 : 0);
    gload16(g, d);
    gload16(g + 8 * (long)lda, d + 1024);
  };
  auto stageB = [&](int buf, int kt, int h) {
    const long ko = (long)kt * 64;
    const u16* g = (h ? gB1 : gB0) + ko;
    char* d = dB + buf * BUF + (h ? 16384 : 0);
    gload16(g, d);
    gload16(g + 8 * (long)ldb, d + 1024);
  };

  // prologue: tile0 (A+B) -> buf0; tile1's B -> buf1.  Drain tile0 only.
  stageA(0, 0, 0);
  stageA(0, 0, 1);
  stageB(0, 0, 0);
  if constexpr (JF == 4) stageB(0, 0, 1);
  stageB(1, 1, 0);
  if constexpr (JF == 4) stageB(1, 1, 1);
  SGB();
  if constexpr (JF == 4)
    asm volatile("s_waitcnt vmcnt(4)" ::: "memory");
  else
    asm volatile("s_waitcnt vmcnt(2)" ::: "memory");
  SGB();
  __builtin_amdgcn_s_barrier();

  for (int s = 0; s < nk; ++s) {
    const int cur = s & 1;
    const bool stA = (s + 1 < nk);
    const bool stB = (s + 2 < nk);
    const char* sb = smem + cur * BUF;
    const char* pA0 = sb + offA0;
    const char* pA1 = sb + offA1;
    const char* pB0 = sb + offB0;
    const char* pB1 = sb + offB1;
#pragma unroll
    for (int p = 0; p < NPH; ++p) {
      // --- phase reads (from buf[cur], staged a full tile ago) ---
      f16x8 af[IPP][2];
#pragma unroll
      for (int ii = 0; ii < IPP; ++ii) {
        af[ii][0] = *(const f16x8*)(pA0 + (p * IPP + ii) * 2048);
        af[ii][1] = *(const f16x8*)(pA1 + (p * IPP + ii) * 2048);
      }
      if (p == 0) {
#pragma unroll
        for (int j = 0; j < JF; ++j) {
          bfrag[0][j] = *(const f16x8*)(pB0 + j * 2048);
          bfrag[1][j] = *(const f16x8*)(pB1 + j * 2048);
        }
      }
      SGB();  // reads pinned before stage issues
      // --- stage issues ---
      if (p == 0 && stA) stageA(cur ^ 1, s + 1, 0);
      if (p == 1) {
        if (stA) stageA(cur ^ 1, s + 1, 1);
        if (stB) stageB(cur, s + 2, 0);
      }
      if constexpr (NPH == 4) {
        if (p == 2 && stB) stageB(cur, s + 2, 1);
      }
      SGB();  // stages pinned before barrier
      __builtin_amdgcn_s_barrier();
      asm volatile("s_waitcnt lgkmcnt(0)" ::: "memory");
      SGB();  // rule #18: MFMAs may not hoist above this point
      __builtin_amdgcn_s_setprio(1);
#pragma unroll
      for (int kk = 0; kk < 2; ++kk)
#pragma unroll
        for (int ii = 0; ii < IPP; ++ii)
#pragma unroll
          for (int j = 0; j < JF; ++j)
            acc[p * IPP + ii][j] = __builtin_amdgcn_mfma_f32_16x16x32_f16(
                af[ii][kk], bfrag[kk][j], acc[p * IPP + ii][j], 0, 0, 0);
      __builtin_amdgcn_s_setprio(0);
      SGB();  // MFMA cluster may not sink below
      if (p == NPH - 1) {
        if (stB) {
          if constexpr (JF == 4)
            asm volatile("s_waitcnt vmcnt(4)" ::: "memory");
          else
            asm volatile("s_waitcnt vmcnt(2)" ::: "memory");
        } else {
          asm volatile("s_waitcnt vmcnt(0)" ::: "memory");
        }
        SGB();
      }
      __builtin_amdgcn_s_barrier();
    }
  }

  // epilogue: C/D: col = lane&15 (fr), row = kgrp*4 + r
#pragma unroll
  for (int i = 0; i < 8; ++i) {
#pragma unroll
    for (int j = 0; j < JF; ++j) {
      const long n = col0 + wn + j * 16 + fr;
      const long m0 = row0 + wm + i * 16 + (kgrp << 2);
      if constexpr (EPI == 3) {
        const float b = aux0[n];
#pragma unroll
        for (int r = 0; r < 4; ++r)
          outU[(m0 + r) * (long)N + n] = f2h(gelu_erf(acc[i][j][r] + b));
      } else {
        const float b = aux0[n];
#pragma unroll
        for (int r = 0; r < 4; ++r) {
          const long idx = (m0 + r) * (long)N + n;
          outF[idx] = acc[i][j][r] + b + h2f(aux1u[idx]);
        }
      }
    }
  }
}

// ---------------------------------------------------------------------------
// LayerNorm over D=1024, one wave per row, 4 rows/block, fp16 out.
// ---------------------------------------------------------------------------
template <bool F32IN>
__global__ __launch_bounds__(256) void ln_k(const void* __restrict__ xin,
                                            const float* __restrict__ gw,
                                            const float* __restrict__ bw,
                                            u16* __restrict__ out) {
  const int lane = threadIdx.x & 63;
  const int wv = threadIdx.x >> 6;
  const long row = (long)blockIdx.x * 4 + wv;
  float4 v[4];
  float s = 0.f, ss = 0.f;
#pragma unroll
  for (int j = 0; j < 4; ++j) {
    const int n = (lane + 64 * j) * 4;
    if constexpr (F32IN) {
      v[j] = *(const float4*)((const float*)xin + row * 1024 + n);
    } else {
      const u16x4 hv = *(const u16x4*)((const u16*)xin + row * 1024 + n);
      v[j] = make_float4(h2f(hv[0]), h2f(hv[1]), h2f(hv[2]), h2f(hv[3]));
    }
    s += v[j].x + v[j].y + v[j].z + v[j].w;
    ss += v[j].x * v[j].x + v[j].y * v[j].y + v[j].z * v[j].z + v[j].w * v[j].w;
  }
#pragma unroll
  for (int o = 32; o; o >>= 1) {
    s += __shfl_xor(s, o);
    ss += __shfl_xor(ss, o);
  }
  const float mu = s * (1.f / 1024.f);
  const float var = ss * (1.f / 1024.f) - mu * mu;
  const float rs = rsqrtf(var + 1e-5f);
  u16* orow = out + row * 1024;
#pragma unroll
  for (int j = 0; j < 4; ++j) {
    const int n = (lane + 64 * j) * 4;
    const float4 gg = *(const float4*)(gw + n);
    const float4 bb = *(const float4*)(bw + n);
    u16x4 H;
    H[0] = f2h((v[j].x - mu) * rs * gg.x + bb.x);
    H[1] = f2h((v[j].y - mu) * rs * gg.y + bb.y);
    H[2] = f2h((v[j].z - mu) * rs * gg.z + bb.z);
    H[3] = f2h((v[j].w - mu) * rs * gg.w + bb.w);
    *(u16x4*)(orow + n) = H;
  }
}

// ---------------------------------------------------------------------------
// Tiled transpose f32 -> fp16. in [R,C] -> out [C,R].
// ---------------------------------------------------------------------------
__global__ __launch_bounds__(256) void transpose_k(const float* __restrict__ in,
                                                   u16* __restrict__ out,
                                                   int R, int C) {
  __shared__ float tile[32][33];
  const int c0 = blockIdx.x * 32, r0 = blockIdx.y * 32;
#pragma unroll
  for (int i = 0; i < 4; ++i) {
    const int lin = threadIdx.x + 256 * i;
    const int rr = lin >> 5, cc = lin & 31;
    tile[rr][cc] = in[(long)(r0 + rr) * C + c0 + cc];
  }
  __syncthreads();
#pragma unroll
  for (int i = 0; i < 4; ++i) {
    const int lin = threadIdx.x + 256 * i;
    const int oc = lin >> 5, orr = lin & 31;
    out[(long)(c0 + oc) * R + (r0 + orr)] = f2h(tile[orr][oc]);
  }
}

// ---------------------------------------------------------------------------
// Row softmax over 2048 cols, f32 in -> fp16 out IN-PLACE.
// ---------------------------------------------------------------------------
__global__ __launch_bounds__(256) void softmax_k(float* __restrict__ S) {
  const long row = blockIdx.x;
  float* sr = S + row * 2048;
  u16* pr = (u16*)sr;
  const int tid = threadIdx.x;
  const int lane = tid & 63, wv = tid >> 6;
  __shared__ float red[8];
  const float4 v0 = *(const float4*)(sr + tid * 4);
  const float4 v1 = *(const float4*)(sr + 1024 + tid * 4);
  float mx = fmaxf(fmaxf(fmaxf(v0.x, v0.y), fmaxf(v0.z, v0.w)),
                   fmaxf(fmaxf(v1.x, v1.y), fmaxf(v1.z, v1.w)));
#pragma unroll
  for (int o = 32; o; o >>= 1) mx = fmaxf(mx, __shfl_xor(mx, o));
  if (lane == 0) red[wv] = mx;
  __syncthreads();
  mx = fmaxf(fmaxf(red[0], red[1]), fmaxf(red[2], red[3]));
  float e[8];
  e[0] = __expf(v0.x - mx); e[1] = __expf(v0.y - mx);
  e[2] = __expf(v0.z - mx); e[3] = __expf(v0.w - mx);
  e[4] = __expf(v1.x - mx); e[5] = __expf(v1.y - mx);
  e[6] = __expf(v1.z - mx); e[7] = __expf(v1.w - mx);
  float sm = e[0] + e[1] + e[2] + e[3] + e[4] + e[5] + e[6] + e[7];
#pragma unroll
  for (int o = 32; o; o >>= 1) sm += __shfl_xor(sm, o);
  if (lane == 0) red[4 + wv] = sm;
  __syncthreads();
  sm = red[4] + red[5] + red[6] + red[7];
  const float inv = 1.f / sm;
  u16x4 a, b;
  a[0] = f2h(e[0] * inv); a[1] = f2h(e[1] * inv);
  a[2] = f2h(e[2] * inv); a[3] = f2h(e[3] * inv);
  b[0] = f2h(e[4] * inv); b[1] = f2h(e[5] * inv);
  b[2] = f2h(e[6] * inv); b[3] = f2h(e[7] * inv);
  *(u16x4*)(pr + tid * 4) = a;
  *(u16x4*)(pr + 1024 + tid * 4) = b;
}

// ---------------------------------------------------------------------------
extern "C" void kernel_launch(void* const* d_in, const int* in_sizes, int n_in,
                              void* d_out, int out_size, void* d_ws,
                              size_t ws_size, hipStream_t stream) {
  const float* x     = (const float*)d_in[0];  // [4,2048,1024]
  const float* w_qkv = (const float*)d_in[1];  // [1024,3072]
  const float* fc1_w = (const float*)d_in[2];  // [1024,4096]
  const float* fc1_b = (const float*)d_in[3];  // [4096]
  const float* fc2_w = (const float*)d_in[4];  // [4096,1024]
  const float* fc2_b = (const float*)d_in[5];  // [1024]
  const float* ln1_g = (const float*)d_in[6];
  const float* ln1_b = (const float*)d_in[7];
  const float* ln2_g = (const float*)d_in[8];
  const float* ln2_b = (const float*)d_in[9];
  float* out = (float*)d_out;

  // workspace (phase-aliased; all fp16 unless noted)
  char* ws = (char*)d_ws;
  const long MB = 1024L * 1024L;
  u16*   h    = (u16*)(ws + 0);          // 16MB [8192,1024]
  u16*   wqkT = (u16*)(ws + 16 * MB);    //  6MB [3072,1024]
  float* sc   = (float*)(ws + 0);        // 64MB f32 scores (h,wqkT dead)
  u16*   qk   = (u16*)(ws + 64 * MB);    // 32MB [8192,2048] (q|k)
  u16*   h2   = (u16*)(ws + 96 * MB);    // 16MB
  u16*   vT   = (u16*)(ws + 112 * MB);   // 16MB [4][1024][2048]
  u16*   w1T  = (u16*)(ws + 144 * MB);   //  8MB [4096,1024]
  u16*   w2T  = (u16*)(ws + 152 * MB);   //  8MB [1024,4096]
  u16*   r2   = (u16*)(ws + 160 * MB);   // 16MB fp16 [8192,1024]
  u16*   g    = (u16*)(ws + 0);          // 64MB [8192,4096] (sc/P dead)

  dim3 blk(256);
  dim3 blk8(512);
  const int LDS4 = 131072;  // JF=4: 2 x (32KB A + 32KB B)
  const int LDS2 = 98304;   // JF=2: 2 x (32KB A + 16KB B)
  (void)hipFuncSetAttribute((const void*)gemm8f<4, 4, 3, true>,
                            hipFuncAttributeMaxDynamicSharedMemorySize, LDS4);
  (void)hipFuncSetAttribute((const void*)gemm8f<2, 2, 4, true>,
                            hipFuncAttributeMaxDynamicSharedMemorySize, LDS2);

  // 1) LN1 -> h fp16
  ln_k<true><<<2048, blk, 0, stream>>>(x, ln1_g, ln1_b, h);
  // 2) w_qkv [1024,3072] -> wqkT [3072,1024] fp16
  transpose_k<<<dim3(3072 / 32, 1024 / 32, 1), blk, 0, stream>>>(w_qkv, wqkT,
                                                                 1024, 3072);
  // 3) qkv-GEMM: h @ wqkv^T -> qk (n<2048) + vT DIRECT.  grid 1536.
  gemm_nt<0, true><<<dim3(24, 64, 1), blk, 0, stream>>>(
      h, wqkT, 8192, 3072, 1024, 1024, 1024, 0, 0, 0, nullptr, qk, vT,
      nullptr, nullptr);
  // 4) GEMM2: scores[z] = q[z] @ k[z]^T (K=1024).  grid 256/z.
  gemm_nt<1, true><<<dim3(16, 16, 4), blk, 0, stream>>>(
      qk, qk + 1024, 2048, 2048, 1024, 2048, 2048, 2048L * 2048, 2048L * 2048,
      2048L * 2048, sc, nullptr, nullptr, nullptr, nullptr);
  // 5) softmax in-place: P (fp16, lda=4096 u16) overwrites score rows
  softmax_k<<<8192, blk, 0, stream>>>(sc);
  // 6) GEMM3: attn = P @ vT + resid(x f32) -> r2 fp16.  grid 128/z.
  gemm_nt<2, true><<<dim3(8, 16, 4), blk, 0, stream>>>(
      (const u16*)sc, vT, 2048, 1024, 2048, 4096, 2048, 2048L * 4096,
      1024L * 2048, 2048L * 1024, nullptr, r2, nullptr, x, nullptr);
  // 7) LN2 (fp16 in) -> h2 fp16
  ln_k<false><<<2048, blk, 0, stream>>>(r2, ln2_g, ln2_b, h2);
  // 8) fc1_w -> w1T, fc2_w -> w2T
  transpose_k<<<dim3(4096 / 32, 1024 / 32, 1), blk, 0, stream>>>(fc1_w, w1T,
                                                                 1024, 4096);
  transpose_k<<<dim3(1024 / 32, 4096 / 32, 1), blk, 0, stream>>>(fc2_w, w2T,
                                                                 4096, 1024);
  // 9) GEMM4 (EXPERIMENT, fenced 8-phase): g = gelu(h2 @ fc1_w + b1).
  //    grid 512 = 2 exact waves at 1 block/CU.
  gemm8f<4, 4, 3, true><<<dim3(16, 32, 1), blk8, LDS4, stream>>>(
      h2, w1T, 8192, 4096, 1024, 1024, 1024, nullptr, g, fc1_b, nullptr);
  // 10) GEMM5 (EXPERIMENT, fenced 8-phase): out = g @ fc2_w + b2 + r2.
  //     grid 256 exact.
  gemm8f<2, 2, 4, true><<<dim3(8, 32, 1), blk8, LDS2, stream>>>(
      g, w2T, 8192, 1024, 4096, 4096, 4096, out, nullptr, fc2_b, r2);
}

// Round 13
// 370.496 us; speedup vs baseline: 1.0384x; 1.0384x over previous
//
#include <hip/hip_runtime.h>
#include <math.h>

typedef unsigned short u16;
typedef unsigned int u32;
typedef _Float16 f16x8 __attribute__((ext_vector_type(8)));
typedef float f32x4 __attribute__((ext_vector_type(4)));
typedef u16 u16x4 __attribute__((ext_vector_type(4)));

__device__ __forceinline__ u16 f2h(float x) {
  _Float16 h = (_Float16)x;
  return __builtin_bit_cast(u16, h);
}
__device__ __forceinline__ float h2f(u16 u) {
  return (float)__builtin_bit_cast(_Float16, u);
}

// exact-erf GELU via Abramowitz-Stegun 7.1.26 (|err| <= 1.5e-7)
__device__ __forceinline__ float gelu_erf(float x) {
  const float u = x * 0.70710678118654752f;
  const float s = fabsf(u);
  const float t = __frcp_rn(1.0f + 0.3275911f * s);
  float p = 1.061405429f;
  p = p * t - 1.453152027f;
  p = p * t + 1.421413741f;
  p = p * t - 0.284496736f;
  p = p * t + 0.254829592f;
  const float e = __expf(-s * s);
  float erf = 1.0f - p * t * e;
  erf = u < 0.0f ? -erf : erf;
  return 0.5f * x * (1.0f + erf);
}

__device__ __forceinline__ void gload16(const void* g, void* l) {
  __builtin_amdgcn_global_load_lds(
      (const __attribute__((address_space(1))) void*)g,
      (__attribute__((address_space(3))) void*)l, 16, 0, 0);
}

// ---------------------------------------------------------------------------
// m97-style NT GEMM, fp16, mfma_f32_16x16x32_f16 (proven engine: 0 bank
// conflicts, ~35% MfmaUtil, ~780 TF).  A [M,lda] rm, B [N,ldb] rm,
// C[m][n] = sum_k A[m][k]*B[n][k].  128x128 tile, BK=64, 4 waves; XOR slot
// swizzle w/ pre-swizzled global source, linear global_load_lds dest.
// EPI: 0 = tv writer (n<1024 -> t; else vT[z][n-1024][m] direct transpose),
//      1 = scores f32, 2 = +resid(aux0 f32) -> fp16 (z-indexed),
//      3 = +bias+gelu -> fp16, 4 = +bias+resid(fp16 aux1u) -> f32 out,
//      5 = plain fp16
// ---------------------------------------------------------------------------
template <int EPI, bool SWZ>
__global__ __launch_bounds__(256, 4) void gemm_nt(
    const u16* __restrict__ A, const u16* __restrict__ B, int M, int N, int K,
    int lda, int ldb, long zsA, long zsB, long zsC, float* __restrict__ outF,
    u16* __restrict__ outU, u16* __restrict__ outU2,
    const float* __restrict__ aux0, const u16* __restrict__ aux1u) {
  __shared__ char smem[2 * 128 * 64 * 2];  // 32 KiB: sA | sB
  char* sA = smem;
  char* sB = smem + 16384;

  const int tid = threadIdx.x;
  const int lane = tid & 63;
  const int wave = tid >> 6;
  const int z = blockIdx.z;

  int bx = blockIdx.x, by = blockIdx.y;
  if constexpr (SWZ) {
    const int gx = gridDim.x;
    const int nwg = gx * gridDim.y;  // all our per-z grids are %8 == 0
    const int id = by * gx + bx;
    const int q = nwg >> 3;
    const int id2 = (id & 7) * q + (id >> 3);
    bx = id2 % gx;
    by = id2 / gx;
  }
  const long row0 = (long)by * 128;
  const long col0 = (long)bx * 128;

  const u16* __restrict__ Ab = A + (long)z * zsA;
  const u16* __restrict__ Bb = B + (long)z * zsB;

  const int srow = lane >> 3;
  const int sslot = (lane & 7) ^ srow;

  const int wm = (wave >> 1) << 6;
  const int wn = (wave & 1) << 6;
  const int fr = lane & 15;
  const int kgrp = lane >> 4;

  f32x4 acc[4][4] = {};
  const int nk = K >> 6;

  auto stage = [&](int kt) {
#pragma unroll
    for (int c = 0; c < 4; ++c) {
      const int chunk = wave * 4 + c;  // 0..15, 8 rows each
      const int r = chunk * 8 + srow;
      gload16(Ab + (row0 + r) * (long)lda + kt * 64 + sslot * 8,
              sA + chunk * 1024);
      gload16(Bb + (col0 + r) * (long)ldb + kt * 64 + sslot * 8,
              sB + chunk * 1024);
    }
  };

  stage(0);
  for (int kt = 0; kt < nk; ++kt) {
    __syncthreads();
#pragma unroll
    for (int kk = 0; kk < 2; ++kk) {
      f16x8 af[4], bg[4];
#pragma unroll
      for (int i = 0; i < 4; ++i) {
        const int r = wm + i * 16 + fr;
        const int slot = ((kk << 2) | kgrp) ^ (r & 7);
        af[i] = *(const f16x8*)(sA + r * 128 + slot * 16);
      }
#pragma unroll
      for (int j = 0; j < 4; ++j) {
        const int r = wn + j * 16 + fr;
        const int slot = ((kk << 2) | kgrp) ^ (r & 7);
        bg[j] = *(const f16x8*)(sB + r * 128 + slot * 16);
      }
#pragma unroll
      for (int i = 0; i < 4; ++i)
#pragma unroll
        for (int j = 0; j < 4; ++j)
          acc[i][j] = __builtin_amdgcn_mfma_f32_16x16x32_f16(af[i], bg[j],
                                                             acc[i][j], 0, 0, 0);
    }
    __syncthreads();
    if (kt + 1 < nk) stage(kt + 1);
  }

  // epilogue: C/D frag layout (verified): col = lane&15, row = kgrp*4 + r
#pragma unroll
  for (int i = 0; i < 4; ++i) {
    const long m0 = row0 + wm + i * 16 + (kgrp << 2);  // r=0..3 contiguous
#pragma unroll
    for (int j = 0; j < 4; ++j) {
      const long n = col0 + wn + j * 16 + fr;
      if constexpr (EPI == 0) {
        if (n < 1024) {
#pragma unroll
          for (int r = 0; r < 4; ++r)
            outU[(m0 + r) * 1024 + n] = f2h(acc[i][j][r]);
        } else {
          // direct V transpose: vT [4][1024][2048] fp16, m contiguous
          u16x4 V;
#pragma unroll
          for (int r = 0; r < 4; ++r) V[r] = f2h(acc[i][j][r]);
          *(u16x4*)(outU2 + ((m0 >> 11) << 21) + (n - 1024) * 2048 +
                    (m0 & 2047)) = V;
        }
      } else if constexpr (EPI == 1) {
#pragma unroll
        for (int r = 0; r < 4; ++r)
          outF[(long)z * zsC + (m0 + r) * (long)N + n] = acc[i][j][r];
      } else if constexpr (EPI == 2) {
#pragma unroll
        for (int r = 0; r < 4; ++r) {
          const long idx = (long)z * zsC + (m0 + r) * (long)N + n;
          outU[idx] = f2h(acc[i][j][r] + aux0[idx]);
        }
      } else if constexpr (EPI == 3) {
        const float b = aux0[n];
#pragma unroll
        for (int r = 0; r < 4; ++r)
          outU[(m0 + r) * (long)N + n] = f2h(gelu_erf(acc[i][j][r] + b));
      } else if constexpr (EPI == 4) {
        const float b = aux0[n];
#pragma unroll
        for (int r = 0; r < 4; ++r) {
          const long idx = (m0 + r) * (long)N + n;
          outF[idx] = acc[i][j][r] + b + h2f(aux1u[idx]);
        }
      } else {
#pragma unroll
        for (int r = 0; r < 4; ++r)
          outU[(m0 + r) * (long)N + n] = f2h(acc[i][j][r]);
      }
    }
  }
}

// ---------------------------------------------------------------------------
// LayerNorm over D=1024, one wave per row, 4 rows/block, fp16 out.
// ---------------------------------------------------------------------------
template <bool F32IN>
__global__ __launch_bounds__(256) void ln_k(const void* __restrict__ xin,
                                            const float* __restrict__ gw,
                                            const float* __restrict__ bw,
                                            u16* __restrict__ out) {
  const int lane = threadIdx.x & 63;
  const int wv = threadIdx.x >> 6;
  const long row = (long)blockIdx.x * 4 + wv;
  float4 v[4];
  float s = 0.f, ss = 0.f;
#pragma unroll
  for (int j = 0; j < 4; ++j) {
    const int n = (lane + 64 * j) * 4;
    if constexpr (F32IN) {
      v[j] = *(const float4*)((const float*)xin + row * 1024 + n);
    } else {
      const u16x4 hv = *(const u16x4*)((const u16*)xin + row * 1024 + n);
      v[j] = make_float4(h2f(hv[0]), h2f(hv[1]), h2f(hv[2]), h2f(hv[3]));
    }
    s += v[j].x + v[j].y + v[j].z + v[j].w;
    ss += v[j].x * v[j].x + v[j].y * v[j].y + v[j].z * v[j].z + v[j].w * v[j].w;
  }
#pragma unroll
  for (int o = 32; o; o >>= 1) {
    s += __shfl_xor(s, o);
    ss += __shfl_xor(ss, o);
  }
  const float mu = s * (1.f / 1024.f);
  const float var = ss * (1.f / 1024.f) - mu * mu;
  const float rs = rsqrtf(var + 1e-5f);
  u16* orow = out + row * 1024;
#pragma unroll
  for (int j = 0; j < 4; ++j) {
    const int n = (lane + 64 * j) * 4;
    const float4 gg = *(const float4*)(gw + n);
    const float4 bb = *(const float4*)(bw + n);
    u16x4 H;
    H[0] = f2h((v[j].x - mu) * rs * gg.x + bb.x);
    H[1] = f2h((v[j].y - mu) * rs * gg.y + bb.y);
    H[2] = f2h((v[j].z - mu) * rs * gg.z + bb.z);
    H[3] = f2h((v[j].w - mu) * rs * gg.w + bb.w);
    *(u16x4*)(orow + n) = H;
  }
}

// ---------------------------------------------------------------------------
// Tiled transpose f32 -> fp16. in rows [R] x logical cols (stride C),
// out [c][r] ld R.  (Pass a column-offset pointer to transpose a slice.)
// ---------------------------------------------------------------------------
__global__ __launch_bounds__(256) void transpose_k(const float* __restrict__ in,
                                                   u16* __restrict__ out,
                                                   int R, int C) {
  __shared__ float tile[32][33];
  const int c0 = blockIdx.x * 32, r0 = blockIdx.y * 32;
#pragma unroll
  for (int i = 0; i < 4; ++i) {
    const int lin = threadIdx.x + 256 * i;
    const int rr = lin >> 5, cc = lin & 31;
    tile[rr][cc] = in[(long)(r0 + rr) * C + c0 + cc];
  }
  __syncthreads();
#pragma unroll
  for (int i = 0; i < 4; ++i) {
    const int lin = threadIdx.x + 256 * i;
    const int oc = lin >> 5, orr = lin & 31;
    out[(long)(c0 + oc) * R + (r0 + orr)] = f2h(tile[orr][oc]);
  }
}

// ---------------------------------------------------------------------------
// Row-major f32 -> fp16 convert: w_qkv [1024][3072] cols 0..2047 ->
// wqk_rm [1024][2048] (NO transpose; keeps output-dim j contiguous so the
// W2 GEMM contracts over j).
// ---------------------------------------------------------------------------
__global__ __launch_bounds__(256) void convert_k(const float* __restrict__ in,
                                                 u16* __restrict__ out) {
  const int idx = blockIdx.x * 256 + threadIdx.x;  // 0 .. 1024*512-1
  const int row = idx >> 9;                        // 512 float4 per row
  const int c = (idx & 511) * 4;
  const float4 v = *(const float4*)(in + (long)row * 3072 + c);
  u16x4 H;
  H[0] = f2h(v.x); H[1] = f2h(v.y); H[2] = f2h(v.z); H[3] = f2h(v.w);
  *(u16x4*)(out + (long)row * 2048 + c) = H;
}

// ---------------------------------------------------------------------------
// Row softmax over 2048 cols, f32 in -> fp16 out IN-PLACE (P overwrites the
// first 4 KB of each 16 KB score row; all reads precede first barrier).
// ---------------------------------------------------------------------------
__global__ __launch_bounds__(256) void softmax_k(float* __restrict__ S) {
  const long row = blockIdx.x;
  float* sr = S + row * 2048;
  u16* pr = (u16*)sr;
  const int tid = threadIdx.x;
  const int lane = tid & 63, wv = tid >> 6;
  __shared__ float red[8];
  const float4 v0 = *(const float4*)(sr + tid * 4);
  const float4 v1 = *(const float4*)(sr + 1024 + tid * 4);
  float mx = fmaxf(fmaxf(fmaxf(v0.x, v0.y), fmaxf(v0.z, v0.w)),
                   fmaxf(fmaxf(v1.x, v1.y), fmaxf(v1.z, v1.w)));
#pragma unroll
  for (int o = 32; o; o >>= 1) mx = fmaxf(mx, __shfl_xor(mx, o));
  if (lane == 0) red[wv] = mx;
  __syncthreads();
  mx = fmaxf(fmaxf(red[0], red[1]), fmaxf(red[2], red[3]));
  float e[8];
  e[0] = __expf(v0.x - mx); e[1] = __expf(v0.y - mx);
  e[2] = __expf(v0.z - mx); e[3] = __expf(v0.w - mx);
  e[4] = __expf(v1.x - mx); e[5] = __expf(v1.y - mx);
  e[6] = __expf(v1.z - mx); e[7] = __expf(v1.w - mx);
  float sm = e[0] + e[1] + e[2] + e[3] + e[4] + e[5] + e[6] + e[7];
#pragma unroll
  for (int o = 32; o; o >>= 1) sm += __shfl_xor(sm, o);
  if (lane == 0) red[4 + wv] = sm;
  __syncthreads();
  sm = red[4] + red[5] + red[6] + red[7];
  const float inv = 1.f / sm;
  u16x4 a, b;
  a[0] = f2h(e[0] * inv); a[1] = f2h(e[1] * inv);
  a[2] = f2h(e[2] * inv); a[3] = f2h(e[3] * inv);
  b[0] = f2h(e[4] * inv); b[1] = f2h(e[5] * inv);
  b[2] = f2h(e[6] * inv); b[3] = f2h(e[7] * inv);
  *(u16x4*)(pr + tid * 4) = a;
  *(u16x4*)(pr + 1024 + tid * 4) = b;
}

// ---------------------------------------------------------------------------
extern "C" void kernel_launch(void* const* d_in, const int* in_sizes, int n_in,
                              void* d_out, int out_size, void* d_ws,
                              size_t ws_size, hipStream_t stream) {
  const float* x     = (const float*)d_in[0];  // [4,2048,1024]
  const float* w_qkv = (const float*)d_in[1];  // [1024,3072]
  const float* fc1_w = (const float*)d_in[2];  // [1024,4096]
  const float* fc1_b = (const float*)d_in[3];  // [4096]
  const float* fc2_w = (const float*)d_in[4];  // [4096,1024]
  const float* fc2_b = (const float*)d_in[5];  // [1024]
  const float* ln1_g = (const float*)d_in[6];
  const float* ln1_b = (const float*)d_in[7];
  const float* ln2_g = (const float*)d_in[8];
  const float* ln2_b = (const float*)d_in[9];
  float* out = (float*)d_out;

  // workspace (phase-aliased; all fp16 unless noted).  Peak 176 MB.
  char* ws = (char*)d_ws;
  const long MB = 1024L * 1024L;
  u16*   h      = (u16*)(ws + 0);          // 16MB [8192,1024]
  u16*   wqk_rm = (u16*)(ws + 16 * MB);    //  4MB [1024,2048] row-major Wq|Wk
  u16*   W2     = (u16*)(ws + 20 * MB);    //  2MB [1024,1024] (Wk Wq^T)[e][d]
  u16*   wvT    = (u16*)(ws + 22 * MB);    //  2MB [1024,1024] (MUST follow W2:
                                           //  tv-GEMM B rows 0..1023=W2,
                                           //  1024..2047=wvT)
  u16*   t      = (u16*)(ws + 24 * MB);    // 16MB [8192,1024] h @ W2^T
  u16*   vT     = (u16*)(ws + 40 * MB);    // 16MB [4][1024][2048]
  float* sc     = (float*)(ws + 64 * MB);  // 64MB f32 scores / P in-place
  u16*   r2     = (u16*)(ws + 128 * MB);   // 16MB fp16 [8192,1024]
  u16*   h2     = (u16*)(ws + 144 * MB);   // 16MB
  u16*   w1T    = (u16*)(ws + 160 * MB);   //  8MB [4096,1024]
  u16*   w2T    = (u16*)(ws + 168 * MB);   //  8MB [1024,4096]
  u16*   g      = (u16*)(ws + 0);          // 64MB [8192,4096] (h..vT dead)

  dim3 blk(256);

  // 1) LN1 -> h fp16
  ln_k<true><<<2048, blk, 0, stream>>>(x, ln1_g, ln1_b, h);
  // 2a) w_qkv cols 0..2047 -> wqk_rm fp16 ROW-MAJOR (j contiguous)
  convert_k<<<2048, blk, 0, stream>>>(w_qkv, wqk_rm);
  // 2b) w_qkv cols 2048..3071 -> wvT [1024,1024] (transposed, for tv-GEMM)
  transpose_k<<<dim3(1024 / 32, 1024 / 32, 1), blk, 0, stream>>>(
      w_qkv + 2048, wvT, 1024, 3072);
  // 3) W2[e][d] = sum_j Wk[e][j]*Wq[d][j]  (contraction over OUTPUT dim j —
  //    this was R12's bug: transposed operands contracted over input dim).
  //    A = wqk_rm+1024 (Wk cols), B = wqk_rm (Wq cols), lda=ldb=2048. grid 64.
  gemm_nt<5, true><<<dim3(8, 8, 1), blk, 0, stream>>>(
      wqk_rm + 1024, wqk_rm, 1024, 1024, 1024, 2048, 2048, 0, 0, 0, nullptr,
      W2, nullptr, nullptr, nullptr);
  // 4) tv-GEMM: A=h, B=[W2|wvT], N=2048 -> t (n<1024) + vT direct. grid 1024.
  //    t[m][e] = sum_d h[m][d]*W2[e][d] = (h · Wq Wk^T)[m][e]
  gemm_nt<0, true><<<dim3(16, 64, 1), blk, 0, stream>>>(
      h, W2, 8192, 2048, 1024, 1024, 1024, 0, 0, 0, nullptr, t, vT, nullptr,
      nullptr);
  // 5) scores[z] = t[z] @ h[z]^T  (associativity: = q @ k^T).  grid 256/z.
  gemm_nt<1, true><<<dim3(16, 16, 4), blk, 0, stream>>>(
      t, h, 2048, 2048, 1024, 1024, 1024, 2048L * 1024, 2048L * 1024,
      2048L * 2048, sc, nullptr, nullptr, nullptr, nullptr);
  // 6) softmax in-place: P (fp16, lda=4096 u16) overwrites score rows
  softmax_k<<<8192, blk, 0, stream>>>(sc);
  // 7) GEMM3: attn = P @ vT + resid(x f32) -> r2 fp16.  grid 128/z.
  gemm_nt<2, true><<<dim3(8, 16, 4), blk, 0, stream>>>(
      (const u16*)sc, vT, 2048, 1024, 2048, 4096, 2048, 2048L * 4096,
      1024L * 2048, 2048L * 1024, nullptr, r2, nullptr, x, nullptr);
  // 8) LN2 (fp16 in) -> h2 fp16
  ln_k<false><<<2048, blk, 0, stream>>>(r2, ln2_g, ln2_b, h2);
  // 9) fc1_w -> w1T, fc2_w -> w2T
  transpose_k<<<dim3(4096 / 32, 1024 / 32, 1), blk, 0, stream>>>(fc1_w, w1T,
                                                                 1024, 4096);
  transpose_k<<<dim3(1024 / 32, 4096 / 32, 1), blk, 0, stream>>>(fc2_w, w2T,
                                                                 4096, 1024);
  // 10) GEMM4: g = gelu(h2 @ fc1_w + b1) fp16.  grid 2048.
  gemm_nt<3, true><<<dim3(32, 64, 1), blk, 0, stream>>>(
      h2, w1T, 8192, 4096, 1024, 1024, 1024, 0, 0, 0, nullptr, g, nullptr,
      fc1_b, nullptr);
  // 11) GEMM5: out = g @ fc2_w + b2 + r2(fp16).  grid 512.
  gemm_nt<4, true><<<dim3(8, 64, 1), blk, 0, stream>>>(
      g, w2T, 8192, 1024, 4096, 4096, 4096, 0, 0, 0, out, nullptr, nullptr,
      fc2_b, r2);
}

// Round 14
// 359.432 us; speedup vs baseline: 1.0703x; 1.0308x over previous
//
#include <hip/hip_runtime.h>
#include <math.h>

typedef unsigned short u16;
typedef unsigned int u32;
typedef _Float16 f16x8 __attribute__((ext_vector_type(8)));
typedef float f32x4 __attribute__((ext_vector_type(4)));
typedef u16 u16x4 __attribute__((ext_vector_type(4)));

__device__ __forceinline__ u16 f2h(float x) {
  _Float16 h = (_Float16)x;
  return __builtin_bit_cast(u16, h);
}
__device__ __forceinline__ float h2f(u16 u) {
  return (float)__builtin_bit_cast(_Float16, u);
}

// exact-erf GELU via Abramowitz-Stegun 7.1.26 (|err| <= 1.5e-7)
__device__ __forceinline__ float gelu_erf(float x) {
  const float u = x * 0.70710678118654752f;
  const float s = fabsf(u);
  const float t = __frcp_rn(1.0f + 0.3275911f * s);
  float p = 1.061405429f;
  p = p * t - 1.453152027f;
  p = p * t + 1.421413741f;
  p = p * t - 0.284496736f;
  p = p * t + 0.254829592f;
  const float e = __expf(-s * s);
  float erf = 1.0f - p * t * e;
  erf = u < 0.0f ? -erf : erf;
  return 0.5f * x * (1.0f + erf);
}

__device__ __forceinline__ void gload16(const void* g, void* l) {
  __builtin_amdgcn_global_load_lds(
      (const __attribute__((address_space(1))) void*)g,
      (__attribute__((address_space(3))) void*)l, 16, 0, 0);
}

// ---------------------------------------------------------------------------
// m97-style NT GEMM, fp16, mfma_f32_16x16x32_f16 (proven engine: 0 bank
// conflicts, ~35% MfmaUtil, ~780 TF).  A [M,lda] rm, B [N,ldb] rm,
// C[m][n] = sum_k A[m][k]*B[n][k].  128x128 tile, BK=64, 4 waves; XOR slot
// swizzle w/ pre-swizzled global source, linear global_load_lds dest.
// EPI: 0 = tv writer (n<1024 -> t; else vT[z][n-1024][m] direct transpose),
//      1 = scores fp16 (z-indexed; R14: was f32 — saves 32MB wr + 32MB rd),
//      2 = +resid(aux0 f32) -> fp16 (z-indexed),
//      3 = +bias+gelu -> fp16, 4 = +bias+resid(fp16 aux1u) -> f32 out,
//      5 = plain fp16
// ---------------------------------------------------------------------------
template <int EPI, bool SWZ>
__global__ __launch_bounds__(256, 4) void gemm_nt(
    const u16* __restrict__ A, const u16* __restrict__ B, int M, int N, int K,
    int lda, int ldb, long zsA, long zsB, long zsC, float* __restrict__ outF,
    u16* __restrict__ outU, u16* __restrict__ outU2,
    const float* __restrict__ aux0, const u16* __restrict__ aux1u) {
  __shared__ char smem[2 * 128 * 64 * 2];  // 32 KiB: sA | sB
  char* sA = smem;
  char* sB = smem + 16384;

  const int tid = threadIdx.x;
  const int lane = tid & 63;
  const int wave = tid >> 6;
  const int z = blockIdx.z;

  int bx = blockIdx.x, by = blockIdx.y;
  if constexpr (SWZ) {
    const int gx = gridDim.x;
    const int nwg = gx * gridDim.y;  // all our per-z grids are %8 == 0
    const int id = by * gx + bx;
    const int q = nwg >> 3;
    const int id2 = (id & 7) * q + (id >> 3);
    bx = id2 % gx;
    by = id2 / gx;
  }
  const long row0 = (long)by * 128;
  const long col0 = (long)bx * 128;

  const u16* __restrict__ Ab = A + (long)z * zsA;
  const u16* __restrict__ Bb = B + (long)z * zsB;

  const int srow = lane >> 3;
  const int sslot = (lane & 7) ^ srow;

  const int wm = (wave >> 1) << 6;
  const int wn = (wave & 1) << 6;
  const int fr = lane & 15;
  const int kgrp = lane >> 4;

  f32x4 acc[4][4] = {};
  const int nk = K >> 6;

  auto stage = [&](int kt) {
#pragma unroll
    for (int c = 0; c < 4; ++c) {
      const int chunk = wave * 4 + c;  // 0..15, 8 rows each
      const int r = chunk * 8 + srow;
      gload16(Ab + (row0 + r) * (long)lda + kt * 64 + sslot * 8,
              sA + chunk * 1024);
      gload16(Bb + (col0 + r) * (long)ldb + kt * 64 + sslot * 8,
              sB + chunk * 1024);
    }
  };

  stage(0);
  for (int kt = 0; kt < nk; ++kt) {
    __syncthreads();
#pragma unroll
    for (int kk = 0; kk < 2; ++kk) {
      f16x8 af[4], bg[4];
#pragma unroll
      for (int i = 0; i < 4; ++i) {
        const int r = wm + i * 16 + fr;
        const int slot = ((kk << 2) | kgrp) ^ (r & 7);
        af[i] = *(const f16x8*)(sA + r * 128 + slot * 16);
      }
#pragma unroll
      for (int j = 0; j < 4; ++j) {
        const int r = wn + j * 16 + fr;
        const int slot = ((kk << 2) | kgrp) ^ (r & 7);
        bg[j] = *(const f16x8*)(sB + r * 128 + slot * 16);
      }
#pragma unroll
      for (int i = 0; i < 4; ++i)
#pragma unroll
        for (int j = 0; j < 4; ++j)
          acc[i][j] = __builtin_amdgcn_mfma_f32_16x16x32_f16(af[i], bg[j],
                                                             acc[i][j], 0, 0, 0);
    }
    __syncthreads();
    if (kt + 1 < nk) stage(kt + 1);
  }

  // epilogue: C/D frag layout (verified): col = lane&15, row = kgrp*4 + r
#pragma unroll
  for (int i = 0; i < 4; ++i) {
    const long m0 = row0 + wm + i * 16 + (kgrp << 2);  // r=0..3 contiguous
#pragma unroll
    for (int j = 0; j < 4; ++j) {
      const long n = col0 + wn + j * 16 + fr;
      if constexpr (EPI == 0) {
        if (n < 1024) {
#pragma unroll
          for (int r = 0; r < 4; ++r)
            outU[(m0 + r) * 1024 + n] = f2h(acc[i][j][r]);
        } else {
          // direct V transpose: vT [4][1024][2048] fp16, m contiguous
          u16x4 V;
#pragma unroll
          for (int r = 0; r < 4; ++r) V[r] = f2h(acc[i][j][r]);
          *(u16x4*)(outU2 + ((m0 >> 11) << 21) + (n - 1024) * 2048 +
                    (m0 & 2047)) = V;
        }
      } else if constexpr (EPI == 1) {
#pragma unroll
        for (int r = 0; r < 4; ++r)
          outU[(long)z * zsC + (m0 + r) * (long)N + n] = f2h(acc[i][j][r]);
      } else if constexpr (EPI == 2) {
#pragma unroll
        for (int r = 0; r < 4; ++r) {
          const long idx = (long)z * zsC + (m0 + r) * (long)N + n;
          outU[idx] = f2h(acc[i][j][r] + aux0[idx]);
        }
      } else if constexpr (EPI == 3) {
        const float b = aux0[n];
#pragma unroll
        for (int r = 0; r < 4; ++r)
          outU[(m0 + r) * (long)N + n] = f2h(gelu_erf(acc[i][j][r] + b));
      } else if constexpr (EPI == 4) {
        const float b = aux0[n];
#pragma unroll
        for (int r = 0; r < 4; ++r) {
          const long idx = (m0 + r) * (long)N + n;
          outF[idx] = acc[i][j][r] + b + h2f(aux1u[idx]);
        }
      } else {
#pragma unroll
        for (int r = 0; r < 4; ++r)
          outU[(m0 + r) * (long)N + n] = f2h(acc[i][j][r]);
      }
    }
  }
}

// ---------------------------------------------------------------------------
// LayerNorm over D=1024, one wave per row, 4 rows/block, fp16 out.
// ---------------------------------------------------------------------------
template <bool F32IN>
__global__ __launch_bounds__(256) void ln_k(const void* __restrict__ xin,
                                            const float* __restrict__ gw,
                                            const float* __restrict__ bw,
                                            u16* __restrict__ out) {
  const int lane = threadIdx.x & 63;
  const int wv = threadIdx.x >> 6;
  const long row = (long)blockIdx.x * 4 + wv;
  float4 v[4];
  float s = 0.f, ss = 0.f;
#pragma unroll
  for (int j = 0; j < 4; ++j) {
    const int n = (lane + 64 * j) * 4;
    if constexpr (F32IN) {
      v[j] = *(const float4*)((const float*)xin + row * 1024 + n);
    } else {
      const u16x4 hv = *(const u16x4*)((const u16*)xin + row * 1024 + n);
      v[j] = make_float4(h2f(hv[0]), h2f(hv[1]), h2f(hv[2]), h2f(hv[3]));
    }
    s += v[j].x + v[j].y + v[j].z + v[j].w;
    ss += v[j].x * v[j].x + v[j].y * v[j].y + v[j].z * v[j].z + v[j].w * v[j].w;
  }
#pragma unroll
  for (int o = 32; o; o >>= 1) {
    s += __shfl_xor(s, o);
    ss += __shfl_xor(ss, o);
  }
  const float mu = s * (1.f / 1024.f);
  const float var = ss * (1.f / 1024.f) - mu * mu;
  const float rs = rsqrtf(var + 1e-5f);
  u16* orow = out + row * 1024;
#pragma unroll
  for (int j = 0; j < 4; ++j) {
    const int n = (lane + 64 * j) * 4;
    const float4 gg = *(const float4*)(gw + n);
    const float4 bb = *(const float4*)(bw + n);
    u16x4 H;
    H[0] = f2h((v[j].x - mu) * rs * gg.x + bb.x);
    H[1] = f2h((v[j].y - mu) * rs * gg.y + bb.y);
    H[2] = f2h((v[j].z - mu) * rs * gg.z + bb.z);
    H[3] = f2h((v[j].w - mu) * rs * gg.w + bb.w);
    *(u16x4*)(orow + n) = H;
  }
}

// ---------------------------------------------------------------------------
// Tiled transpose f32 -> fp16. in rows [R] x logical cols (stride C),
// out [c][r] ld R.  (Pass a column-offset pointer to transpose a slice.)
// ---------------------------------------------------------------------------
__global__ __launch_bounds__(256) void transpose_k(const float* __restrict__ in,
                                                   u16* __restrict__ out,
                                                   int R, int C) {
  __shared__ float tile[32][33];
  const int c0 = blockIdx.x * 32, r0 = blockIdx.y * 32;
#pragma unroll
  for (int i = 0; i < 4; ++i) {
    const int lin = threadIdx.x + 256 * i;
    const int rr = lin >> 5, cc = lin & 31;
    tile[rr][cc] = in[(long)(r0 + rr) * C + c0 + cc];
  }
  __syncthreads();
#pragma unroll
  for (int i = 0; i < 4; ++i) {
    const int lin = threadIdx.x + 256 * i;
    const int oc = lin >> 5, orr = lin & 31;
    out[(long)(c0 + oc) * R + (r0 + orr)] = f2h(tile[orr][oc]);
  }
}

// ---------------------------------------------------------------------------
// Row-major f32 -> fp16 convert: w_qkv [1024][3072] cols 0..2047 ->
// wqk_rm [1024][2048] (NO transpose; keeps output-dim j contiguous so the
// W2 GEMM contracts over j).
// ---------------------------------------------------------------------------
__global__ __launch_bounds__(256) void convert_k(const float* __restrict__ in,
                                                 u16* __restrict__ out) {
  const int idx = blockIdx.x * 256 + threadIdx.x;  // 0 .. 1024*512-1
  const int row = idx >> 9;                        // 512 float4 per row
  const int c = (idx & 511) * 4;
  const float4 v = *(const float4*)(in + (long)row * 3072 + c);
  u16x4 H;
  H[0] = f2h(v.x); H[1] = f2h(v.y); H[2] = f2h(v.z); H[3] = f2h(v.w);
  *(u16x4*)(out + (long)row * 2048 + c) = H;
}

// ---------------------------------------------------------------------------
// Row softmax over 2048 cols, fp16 in -> fp16 out IN-PLACE (one block/row;
// all reads precede the first barrier, writes follow the last).
// ---------------------------------------------------------------------------
__global__ __launch_bounds__(256) void softmax_k(u16* __restrict__ S) {
  const long row = blockIdx.x;
  u16* sr = S + row * 2048;
  const int tid = threadIdx.x;
  const int lane = tid & 63, wv = tid >> 6;
  __shared__ float red[8];
  const u16x4 a0 = *(const u16x4*)(sr + tid * 4);
  const u16x4 a1 = *(const u16x4*)(sr + 1024 + tid * 4);
  float v[8];
  v[0] = h2f(a0[0]); v[1] = h2f(a0[1]); v[2] = h2f(a0[2]); v[3] = h2f(a0[3]);
  v[4] = h2f(a1[0]); v[5] = h2f(a1[1]); v[6] = h2f(a1[2]); v[7] = h2f(a1[3]);
  float mx = fmaxf(fmaxf(fmaxf(v[0], v[1]), fmaxf(v[2], v[3])),
                   fmaxf(fmaxf(v[4], v[5]), fmaxf(v[6], v[7])));
#pragma unroll
  for (int o = 32; o; o >>= 1) mx = fmaxf(mx, __shfl_xor(mx, o));
  if (lane == 0) red[wv] = mx;
  __syncthreads();
  mx = fmaxf(fmaxf(red[0], red[1]), fmaxf(red[2], red[3]));
  float e[8];
#pragma unroll
  for (int c = 0; c < 8; ++c) e[c] = __expf(v[c] - mx);
  float sm = e[0] + e[1] + e[2] + e[3] + e[4] + e[5] + e[6] + e[7];
#pragma unroll
  for (int o = 32; o; o >>= 1) sm += __shfl_xor(sm, o);
  if (lane == 0) red[4 + wv] = sm;
  __syncthreads();
  sm = red[4] + red[5] + red[6] + red[7];
  const float inv = 1.f / sm;
  u16x4 b0, b1;
  b0[0] = f2h(e[0] * inv); b0[1] = f2h(e[1] * inv);
  b0[2] = f2h(e[2] * inv); b0[3] = f2h(e[3] * inv);
  b1[0] = f2h(e[4] * inv); b1[1] = f2h(e[5] * inv);
  b1[2] = f2h(e[6] * inv); b1[3] = f2h(e[7] * inv);
  *(u16x4*)(sr + tid * 4) = b0;
  *(u16x4*)(sr + 1024 + tid * 4) = b1;
}

// ---------------------------------------------------------------------------
extern "C" void kernel_launch(void* const* d_in, const int* in_sizes, int n_in,
                              void* d_out, int out_size, void* d_ws,
                              size_t ws_size, hipStream_t stream) {
  const float* x     = (const float*)d_in[0];  // [4,2048,1024]
  const float* w_qkv = (const float*)d_in[1];  // [1024,3072]
  const float* fc1_w = (const float*)d_in[2];  // [1024,4096]
  const float* fc1_b = (const float*)d_in[3];  // [4096]
  const float* fc2_w = (const float*)d_in[4];  // [4096,1024]
  const float* fc2_b = (const float*)d_in[5];  // [1024]
  const float* ln1_g = (const float*)d_in[6];
  const float* ln1_b = (const float*)d_in[7];
  const float* ln2_g = (const float*)d_in[8];
  const float* ln2_b = (const float*)d_in[9];
  float* out = (float*)d_out;

  // workspace (phase-aliased; all fp16 unless noted).  Peak 144 MB.
  char* ws = (char*)d_ws;
  const long MB = 1024L * 1024L;
  u16*   h      = (u16*)(ws + 0);          // 16MB [8192,1024]
  u16*   wqk_rm = (u16*)(ws + 16 * MB);    //  4MB [1024,2048] row-major Wq|Wk
  u16*   W2     = (u16*)(ws + 20 * MB);    //  2MB [1024,1024] (Wk Wq^T)[e][d]
  u16*   wvT    = (u16*)(ws + 22 * MB);    //  2MB [1024,1024] (MUST follow W2:
                                           //  tv-GEMM B rows 0..1023=W2,
                                           //  1024..2047=wvT)
  u16*   t      = (u16*)(ws + 24 * MB);    // 16MB [8192,1024] h @ W2^T
  u16*   vT     = (u16*)(ws + 40 * MB);    // 16MB [4][1024][2048]
  u16*   sc16   = (u16*)(ws + 64 * MB);    // 32MB fp16 scores / P in-place
  u16*   r2     = (u16*)(ws + 96 * MB);    // 16MB fp16 [8192,1024]
  u16*   h2     = (u16*)(ws + 112 * MB);   // 16MB
  u16*   w1T    = (u16*)(ws + 128 * MB);   //  8MB [4096,1024]
  u16*   w2T    = (u16*)(ws + 136 * MB);   //  8MB [1024,4096]
  u16*   g      = (u16*)(ws + 0);          // 64MB [8192,4096] (h..vT dead)

  dim3 blk(256);

  // 1) LN1 -> h fp16
  ln_k<true><<<2048, blk, 0, stream>>>(x, ln1_g, ln1_b, h);
  // 2a) w_qkv cols 0..2047 -> wqk_rm fp16 ROW-MAJOR (j contiguous)
  convert_k<<<2048, blk, 0, stream>>>(w_qkv, wqk_rm);
  // 2b) w_qkv cols 2048..3071 -> wvT [1024,1024] (transposed, for tv-GEMM)
  transpose_k<<<dim3(1024 / 32, 1024 / 32, 1), blk, 0, stream>>>(
      w_qkv + 2048, wvT, 1024, 3072);
  // 3) W2[e][d] = sum_j Wk[e][j]*Wq[d][j]  (contraction over output dim j).
  gemm_nt<5, true><<<dim3(8, 8, 1), blk, 0, stream>>>(
      wqk_rm + 1024, wqk_rm, 1024, 1024, 1024, 2048, 2048, 0, 0, 0, nullptr,
      W2, nullptr, nullptr, nullptr);
  // 4) tv-GEMM: A=h, B=[W2|wvT], N=2048 -> t (n<1024) + vT direct. grid 1024.
  gemm_nt<0, true><<<dim3(16, 64, 1), blk, 0, stream>>>(
      h, W2, 8192, 2048, 1024, 1024, 1024, 0, 0, 0, nullptr, t, vT, nullptr,
      nullptr);
  // 5) scores[z] = t[z] @ h[z]^T -> fp16 (R14: halves the scores round-trip).
  gemm_nt<1, true><<<dim3(16, 16, 4), blk, 0, stream>>>(
      t, h, 2048, 2048, 1024, 1024, 1024, 2048L * 1024, 2048L * 1024,
      2048L * 2048, nullptr, sc16, nullptr, nullptr, nullptr);
  // 6) softmax in-place on fp16 scores -> P fp16 (lda 2048)
  softmax_k<<<8192, blk, 0, stream>>>(sc16);
  // 7) GEMM3: attn = P @ vT + resid(x f32) -> r2 fp16.  grid 128/z.
  gemm_nt<2, true><<<dim3(8, 16, 4), blk, 0, stream>>>(
      sc16, vT, 2048, 1024, 2048, 2048, 2048, 2048L * 2048, 1024L * 2048,
      2048L * 1024, nullptr, r2, nullptr, x, nullptr);
  // 8) LN2 (fp16 in) -> h2 fp16
  ln_k<false><<<2048, blk, 0, stream>>>(r2, ln2_g, ln2_b, h2);
  // 9) fc1_w -> w1T, fc2_w -> w2T
  transpose_k<<<dim3(4096 / 32, 1024 / 32, 1), blk, 0, stream>>>(fc1_w, w1T,
                                                                 1024, 4096);
  transpose_k<<<dim3(1024 / 32, 4096 / 32, 1), blk, 0, stream>>>(fc2_w, w2T,
                                                                 4096, 1024);
  // 10) GEMM4: g = gelu(h2 @ fc1_w + b1) fp16.  grid 2048.
  gemm_nt<3, true><<<dim3(32, 64, 1), blk, 0, stream>>>(
      h2, w1T, 8192, 4096, 1024, 1024, 1024, 0, 0, 0, nullptr, g, nullptr,
      fc1_b, nullptr);
  // 11) GEMM5: out = g @ fc2_w + b2 + r2(fp16).  grid 512.
  gemm_nt<4, true><<<dim3(8, 64, 1), blk, 0, stream>>>(
      g, w2T, 8192, 1024, 4096, 4096, 4096, 0, 0, 0, out, nullptr, nullptr,
      fc2_b, r2);
}

// Round 15
// 359.154 us; speedup vs baseline: 1.0712x; 1.0008x over previous
//
#include <hip/hip_runtime.h>
#include <math.h>

typedef unsigned short u16;
typedef unsigned int u32;
typedef _Float16 f16x8 __attribute__((ext_vector_type(8)));
typedef float f32x4 __attribute__((ext_vector_type(4)));
typedef u16 u16x4 __attribute__((ext_vector_type(4)));
typedef u16 u16x8 __attribute__((ext_vector_type(8)));

__device__ __forceinline__ u16 f2h(float x) {
  _Float16 h = (_Float16)x;
  return __builtin_bit_cast(u16, h);
}
__device__ __forceinline__ float h2f(u16 u) {
  return (float)__builtin_bit_cast(_Float16, u);
}

// exact-erf GELU via Abramowitz-Stegun 7.1.26 (|err| <= 1.5e-7)
__device__ __forceinline__ float gelu_erf(float x) {
  const float u = x * 0.70710678118654752f;
  const float s = fabsf(u);
  const float t = __frcp_rn(1.0f + 0.3275911f * s);
  float p = 1.061405429f;
  p = p * t - 1.453152027f;
  p = p * t + 1.421413741f;
  p = p * t - 0.284496736f;
  p = p * t + 0.254829592f;
  const float e = __expf(-s * s);
  float erf = 1.0f - p * t * e;
  erf = u < 0.0f ? -erf : erf;
  return 0.5f * x * (1.0f + erf);
}

__device__ __forceinline__ void gload16(const void* g, void* l) {
  __builtin_amdgcn_global_load_lds(
      (const __attribute__((address_space(1))) void*)g,
      (__attribute__((address_space(3))) void*)l, 16, 0, 0);
}

// ---------------------------------------------------------------------------
// m97-style NT GEMM, fp16, mfma_f32_16x16x32_f16 (proven engine: 0 bank
// conflicts, ~35% MfmaUtil, ~780 TF).  A [M,lda] rm, B [N,ldb] rm,
// C[m][n] = sum_k A[m][k]*B[n][k].  128x128 tile, BK=64, 4 waves; XOR slot
// swizzle w/ pre-swizzled global source, linear global_load_lds dest.
// EPI: 0 = tv writer (n<1024 -> t; else vT[z][n-1024][m] direct transpose),
//      1 = scores fp16 (z-indexed), 2 = +resid(aux0 f32) -> fp16 (z-indexed),
//      3 = +bias+gelu -> fp16, 4 = +bias+resid(fp16 aux1u) -> f32 out,
//      5 = plain fp16
// ---------------------------------------------------------------------------
template <int EPI, bool SWZ>
__global__ __launch_bounds__(256, 4) void gemm_nt(
    const u16* __restrict__ A, const u16* __restrict__ B, int M, int N, int K,
    int lda, int ldb, long zsA, long zsB, long zsC, float* __restrict__ outF,
    u16* __restrict__ outU, u16* __restrict__ outU2,
    const float* __restrict__ aux0, const u16* __restrict__ aux1u) {
  __shared__ char smem[2 * 128 * 64 * 2];  // 32 KiB: sA | sB
  char* sA = smem;
  char* sB = smem + 16384;

  const int tid = threadIdx.x;
  const int lane = tid & 63;
  const int wave = tid >> 6;
  const int z = blockIdx.z;

  int bx = blockIdx.x, by = blockIdx.y;
  if constexpr (SWZ) {
    const int gx = gridDim.x;
    const int nwg = gx * gridDim.y;  // all our per-z grids are %8 == 0
    const int id = by * gx + bx;
    const int q = nwg >> 3;
    const int id2 = (id & 7) * q + (id >> 3);
    bx = id2 % gx;
    by = id2 / gx;
  }
  const long row0 = (long)by * 128;
  const long col0 = (long)bx * 128;

  const u16* __restrict__ Ab = A + (long)z * zsA;
  const u16* __restrict__ Bb = B + (long)z * zsB;

  const int srow = lane >> 3;
  const int sslot = (lane & 7) ^ srow;

  const int wm = (wave >> 1) << 6;
  const int wn = (wave & 1) << 6;
  const int fr = lane & 15;
  const int kgrp = lane >> 4;

  f32x4 acc[4][4] = {};
  const int nk = K >> 6;

  auto stage = [&](int kt) {
#pragma unroll
    for (int c = 0; c < 4; ++c) {
      const int chunk = wave * 4 + c;  // 0..15, 8 rows each
      const int r = chunk * 8 + srow;
      gload16(Ab + (row0 + r) * (long)lda + kt * 64 + sslot * 8,
              sA + chunk * 1024);
      gload16(Bb + (col0 + r) * (long)ldb + kt * 64 + sslot * 8,
              sB + chunk * 1024);
    }
  };

  stage(0);
  for (int kt = 0; kt < nk; ++kt) {
    __syncthreads();
#pragma unroll
    for (int kk = 0; kk < 2; ++kk) {
      f16x8 af[4], bg[4];
#pragma unroll
      for (int i = 0; i < 4; ++i) {
        const int r = wm + i * 16 + fr;
        const int slot = ((kk << 2) | kgrp) ^ (r & 7);
        af[i] = *(const f16x8*)(sA + r * 128 + slot * 16);
      }
#pragma unroll
      for (int j = 0; j < 4; ++j) {
        const int r = wn + j * 16 + fr;
        const int slot = ((kk << 2) | kgrp) ^ (r & 7);
        bg[j] = *(const f16x8*)(sB + r * 128 + slot * 16);
      }
#pragma unroll
      for (int i = 0; i < 4; ++i)
#pragma unroll
        for (int j = 0; j < 4; ++j)
          acc[i][j] = __builtin_amdgcn_mfma_f32_16x16x32_f16(af[i], bg[j],
                                                             acc[i][j], 0, 0, 0);
    }
    __syncthreads();
    if (kt + 1 < nk) stage(kt + 1);
  }

  // epilogue: C/D frag layout (verified): col = lane&15, row = kgrp*4 + r
#pragma unroll
  for (int i = 0; i < 4; ++i) {
    const long m0 = row0 + wm + i * 16 + (kgrp << 2);  // r=0..3 contiguous
#pragma unroll
    for (int j = 0; j < 4; ++j) {
      const long n = col0 + wn + j * 16 + fr;
      if constexpr (EPI == 0) {
        if (n < 1024) {
#pragma unroll
          for (int r = 0; r < 4; ++r)
            outU[(m0 + r) * 1024 + n] = f2h(acc[i][j][r]);
        } else {
          // direct V transpose: vT [4][1024][2048] fp16, m contiguous
          u16x4 V;
#pragma unroll
          for (int r = 0; r < 4; ++r) V[r] = f2h(acc[i][j][r]);
          *(u16x4*)(outU2 + ((m0 >> 11) << 21) + (n - 1024) * 2048 +
                    (m0 & 2047)) = V;
        }
      } else if constexpr (EPI == 1) {
#pragma unroll
        for (int r = 0; r < 4; ++r)
          outU[(long)z * zsC + (m0 + r) * (long)N + n] = f2h(acc[i][j][r]);
      } else if constexpr (EPI == 2) {
#pragma unroll
        for (int r = 0; r < 4; ++r) {
          const long idx = (long)z * zsC + (m0 + r) * (long)N + n;
          outU[idx] = f2h(acc[i][j][r] + aux0[idx]);
        }
      } else if constexpr (EPI == 3) {
        const float b = aux0[n];
#pragma unroll
        for (int r = 0; r < 4; ++r)
          outU[(m0 + r) * (long)N + n] = f2h(gelu_erf(acc[i][j][r] + b));
      } else if constexpr (EPI == 4) {
        const float b = aux0[n];
#pragma unroll
        for (int r = 0; r < 4; ++r) {
          const long idx = (m0 + r) * (long)N + n;
          outF[idx] = acc[i][j][r] + b + h2f(aux1u[idx]);
        }
      } else {
#pragma unroll
        for (int r = 0; r < 4; ++r)
          outU[(m0 + r) * (long)N + n] = f2h(acc[i][j][r]);
      }
    }
  }
}

// ---------------------------------------------------------------------------
// LayerNorm over D=1024, one wave per row, 4 rows/block, fp16 out.
// ---------------------------------------------------------------------------
template <bool F32IN>
__global__ __launch_bounds__(256) void ln_k(const void* __restrict__ xin,
                                            const float* __restrict__ gw,
                                            const float* __restrict__ bw,
                                            u16* __restrict__ out) {
  const int lane = threadIdx.x & 63;
  const int wv = threadIdx.x >> 6;
  const long row = (long)blockIdx.x * 4 + wv;
  float4 v[4];
  float s = 0.f, ss = 0.f;
#pragma unroll
  for (int j = 0; j < 4; ++j) {
    const int n = (lane + 64 * j) * 4;
    if constexpr (F32IN) {
      v[j] = *(const float4*)((const float*)xin + row * 1024 + n);
    } else {
      const u16x4 hv = *(const u16x4*)((const u16*)xin + row * 1024 + n);
      v[j] = make_float4(h2f(hv[0]), h2f(hv[1]), h2f(hv[2]), h2f(hv[3]));
    }
    s += v[j].x + v[j].y + v[j].z + v[j].w;
    ss += v[j].x * v[j].x + v[j].y * v[j].y + v[j].z * v[j].z + v[j].w * v[j].w;
  }
#pragma unroll
  for (int o = 32; o; o >>= 1) {
    s += __shfl_xor(s, o);
    ss += __shfl_xor(ss, o);
  }
  const float mu = s * (1.f / 1024.f);
  const float var = ss * (1.f / 1024.f) - mu * mu;
  const float rs = rsqrtf(var + 1e-5f);
  u16* orow = out + row * 1024;
#pragma unroll
  for (int j = 0; j < 4; ++j) {
    const int n = (lane + 64 * j) * 4;
    const float4 gg = *(const float4*)(gw + n);
    const float4 bb = *(const float4*)(bw + n);
    u16x4 H;
    H[0] = f2h((v[j].x - mu) * rs * gg.x + bb.x);
    H[1] = f2h((v[j].y - mu) * rs * gg.y + bb.y);
    H[2] = f2h((v[j].z - mu) * rs * gg.z + bb.z);
    H[3] = f2h((v[j].w - mu) * rs * gg.w + bb.w);
    *(u16x4*)(orow + n) = H;
  }
}

// ---------------------------------------------------------------------------
// Tiled transpose f32 -> fp16. in rows [R] x logical cols (stride C),
// out [c][r] ld R.  (Pass a column-offset pointer to transpose a slice.)
// ---------------------------------------------------------------------------
__global__ __launch_bounds__(256) void transpose_k(const float* __restrict__ in,
                                                   u16* __restrict__ out,
                                                   int R, int C) {
  __shared__ float tile[32][33];
  const int c0 = blockIdx.x * 32, r0 = blockIdx.y * 32;
#pragma unroll
  for (int i = 0; i < 4; ++i) {
    const int lin = threadIdx.x + 256 * i;
    const int rr = lin >> 5, cc = lin & 31;
    tile[rr][cc] = in[(long)(r0 + rr) * C + c0 + cc];
  }
  __syncthreads();
#pragma unroll
  for (int i = 0; i < 4; ++i) {
    const int lin = threadIdx.x + 256 * i;
    const int oc = lin >> 5, orr = lin & 31;
    out[(long)(c0 + oc) * R + (r0 + orr)] = f2h(tile[orr][oc]);
  }
}

// ---------------------------------------------------------------------------
// Row-major f32 -> fp16 convert: w_qkv [1024][3072] cols 0..2047 ->
// wqk_rm [1024][2048] (NO transpose; keeps output-dim j contiguous so the
// W2 GEMM contracts over j).
// ---------------------------------------------------------------------------
__global__ __launch_bounds__(256) void convert_k(const float* __restrict__ in,
                                                 u16* __restrict__ out) {
  const int idx = blockIdx.x * 256 + threadIdx.x;  // 0 .. 1024*512-1
  const int row = idx >> 9;                        // 512 float4 per row
  const int c = (idx & 511) * 4;
  const float4 v = *(const float4*)(in + (long)row * 3072 + c);
  u16x4 H;
  H[0] = f2h(v.x); H[1] = f2h(v.y); H[2] = f2h(v.z); H[3] = f2h(v.w);
  *(u16x4*)(out + (long)row * 2048 + c) = H;
}

// ---------------------------------------------------------------------------
// Row softmax over 2048 cols, fp16 in -> fp16 out IN-PLACE.  One block/row;
// one u16x8 (16B) load + store per thread (G13 coalescing sweet spot).
// ---------------------------------------------------------------------------
__global__ __launch_bounds__(256) void softmax_k(u16* __restrict__ S) {
  const long row = blockIdx.x;
  u16* sr = S + row * 2048;
  const int tid = threadIdx.x;
  const int lane = tid & 63, wv = tid >> 6;
  __shared__ float red[8];
  const u16x8 a = *(const u16x8*)(sr + tid * 8);
  float v[8];
#pragma unroll
  for (int c = 0; c < 8; ++c) v[c] = h2f(a[c]);
  float mx = fmaxf(fmaxf(fmaxf(v[0], v[1]), fmaxf(v[2], v[3])),
                   fmaxf(fmaxf(v[4], v[5]), fmaxf(v[6], v[7])));
#pragma unroll
  for (int o = 32; o; o >>= 1) mx = fmaxf(mx, __shfl_xor(mx, o));
  if (lane == 0) red[wv] = mx;
  __syncthreads();
  mx = fmaxf(fmaxf(red[0], red[1]), fmaxf(red[2], red[3]));
  float e[8];
#pragma unroll
  for (int c = 0; c < 8; ++c) e[c] = __expf(v[c] - mx);
  float sm = e[0] + e[1] + e[2] + e[3] + e[4] + e[5] + e[6] + e[7];
#pragma unroll
  for (int o = 32; o; o >>= 1) sm += __shfl_xor(sm, o);
  if (lane == 0) red[4 + wv] = sm;
  __syncthreads();
  sm = red[4] + red[5] + red[6] + red[7];
  const float inv = 1.f / sm;
  u16x8 b;
#pragma unroll
  for (int c = 0; c < 8; ++c) b[c] = f2h(e[c] * inv);
  *(u16x8*)(sr + tid * 8) = b;
}

// ---------------------------------------------------------------------------
extern "C" void kernel_launch(void* const* d_in, const int* in_sizes, int n_in,
                              void* d_out, int out_size, void* d_ws,
                              size_t ws_size, hipStream_t stream) {
  const float* x     = (const float*)d_in[0];  // [4,2048,1024]
  const float* w_qkv = (const float*)d_in[1];  // [1024,3072]
  const float* fc1_w = (const float*)d_in[2];  // [1024,4096]
  const float* fc1_b = (const float*)d_in[3];  // [4096]
  const float* fc2_w = (const float*)d_in[4];  // [4096,1024]
  const float* fc2_b = (const float*)d_in[5];  // [1024]
  const float* ln1_g = (const float*)d_in[6];
  const float* ln1_b = (const float*)d_in[7];
  const float* ln2_g = (const float*)d_in[8];
  const float* ln2_b = (const float*)d_in[9];
  float* out = (float*)d_out;

  // workspace (phase-aliased; all fp16 unless noted).  Peak 144 MB.
  char* ws = (char*)d_ws;
  const long MB = 1024L * 1024L;
  u16*   h      = (u16*)(ws + 0);          // 16MB [8192,1024]
  u16*   wqk_rm = (u16*)(ws + 16 * MB);    //  4MB [1024,2048] row-major Wq|Wk
  u16*   W2     = (u16*)(ws + 20 * MB);    //  2MB [1024,1024] (Wk Wq^T)[e][d]
  u16*   wvT    = (u16*)(ws + 22 * MB);    //  2MB [1024,1024] (MUST follow W2:
                                           //  tv-GEMM B rows 0..1023=W2,
                                           //  1024..2047=wvT)
  u16*   t      = (u16*)(ws + 24 * MB);    // 16MB [8192,1024] h @ W2^T
  u16*   vT     = (u16*)(ws + 40 * MB);    // 16MB [4][1024][2048]
  u16*   sc16   = (u16*)(ws + 64 * MB);    // 32MB fp16 scores / P in-place
  u16*   r2     = (u16*)(ws + 96 * MB);    // 16MB fp16 [8192,1024]
  u16*   h2     = (u16*)(ws + 112 * MB);   // 16MB
  u16*   w1T    = (u16*)(ws + 128 * MB);   //  8MB [4096,1024]
  u16*   w2T    = (u16*)(ws + 136 * MB);   //  8MB [1024,4096]
  u16*   g      = (u16*)(ws + 0);          // 64MB [8192,4096] (h..vT dead)

  dim3 blk(256);

  // 1) LN1 -> h fp16
  ln_k<true><<<2048, blk, 0, stream>>>(x, ln1_g, ln1_b, h);
  // 2a) w_qkv cols 0..2047 -> wqk_rm fp16 ROW-MAJOR (j contiguous)
  convert_k<<<2048, blk, 0, stream>>>(w_qkv, wqk_rm);
  // 2b) w_qkv cols 2048..3071 -> wvT [1024,1024] (transposed, for tv-GEMM)
  transpose_k<<<dim3(1024 / 32, 1024 / 32, 1), blk, 0, stream>>>(
      w_qkv + 2048, wvT, 1024, 3072);
  // 3) W2[e][d] = sum_j Wk[e][j]*Wq[d][j]  (contraction over output dim j).
  gemm_nt<5, true><<<dim3(8, 8, 1), blk, 0, stream>>>(
      wqk_rm + 1024, wqk_rm, 1024, 1024, 1024, 2048, 2048, 0, 0, 0, nullptr,
      W2, nullptr, nullptr, nullptr);
  // 4) tv-GEMM: A=h, B=[W2|wvT], N=2048 -> t (n<1024) + vT direct. grid 1024.
  gemm_nt<0, true><<<dim3(16, 64, 1), blk, 0, stream>>>(
      h, W2, 8192, 2048, 1024, 1024, 1024, 0, 0, 0, nullptr, t, vT, nullptr,
      nullptr);
  // 5) scores[z] = t[z] @ h[z]^T -> fp16
  gemm_nt<1, true><<<dim3(16, 16, 4), blk, 0, stream>>>(
      t, h, 2048, 2048, 1024, 1024, 1024, 2048L * 1024, 2048L * 1024,
      2048L * 2048, nullptr, sc16, nullptr, nullptr, nullptr);
  // 6) softmax in-place on fp16 scores -> P fp16 (lda 2048)
  softmax_k<<<8192, blk, 0, stream>>>(sc16);
  // 7) GEMM3: attn = P @ vT + resid(x f32) -> r2 fp16.  grid 128/z.
  gemm_nt<2, true><<<dim3(8, 16, 4), blk, 0, stream>>>(
      sc16, vT, 2048, 1024, 2048, 2048, 2048, 2048L * 2048, 1024L * 2048,
      2048L * 1024, nullptr, r2, nullptr, x, nullptr);
  // 8) LN2 (fp16 in) -> h2 fp16
  ln_k<false><<<2048, blk, 0, stream>>>(r2, ln2_g, ln2_b, h2);
  // 9) fc1_w -> w1T, fc2_w -> w2T
  transpose_k<<<dim3(4096 / 32, 1024 / 32, 1), blk, 0, stream>>>(fc1_w, w1T,
                                                                 1024, 4096);
  transpose_k<<<dim3(1024 / 32, 4096 / 32, 1), blk, 0, stream>>>(fc2_w, w2T,
                                                                 4096, 1024);
  // 10) GEMM4: g = gelu(h2 @ fc1_w + b1) fp16.  grid 2048.
  gemm_nt<3, true><<<dim3(32, 64, 1), blk, 0, stream>>>(
      h2, w1T, 8192, 4096, 1024, 1024, 1024, 0, 0, 0, nullptr, g, nullptr,
      fc1_b, nullptr);
  // 11) GEMM5: out = g @ fc2_w + b2 + r2(fp16).  grid 512.
  gemm_nt<4, true><<<dim3(8, 64, 1), blk, 0, stream>>>(
      g, w2T, 8192, 1024, 4096, 4096, 4096, 0, 0, 0, out, nullptr, nullptr,
      fc2_b, r2);
}